// Round 13
// baseline (703.200 us; speedup 1.0000x reference)
//
#include <hip/hip_runtime.h>

// ---------------- constants ----------------
constexpr int NT = 64;     // timesteps
constexpr int NB = 64;     // batch
constexpr int NV = 32000;  // vocab
constexpr int NE = 512;    // embed
constexpr int NH = 512;    // hidden
// wg classes: [0,64) l0A | [64,128) l1A | [128,160) l0B | [160,192) l1B | [192,256) gemm
constexpr int NQUAD = 16 * 125;   // gemm steals: (bm-pair, bn-pair) = 256x256 output

constexpr size_t SZ_OW  = (size_t)NV * NE;
constexpr size_t SZ_XE  = (size_t)NT * NB * NE;
constexpr size_t SZ_H   = (size_t)NB * NH;
constexpr size_t LOGITS = (size_t)NT * NB * NV;

typedef float f32x4 __attribute__((ext_vector_type(4)));
typedef int   i32x4 __attribute__((ext_vector_type(4)));
typedef short bf16x8 __attribute__((ext_vector_type(8)));
typedef short s16x4 __attribute__((ext_vector_type(4)));
typedef _Float16 f16x8 __attribute__((ext_vector_type(8)));

// ---------------- helpers ----------------
__device__ __forceinline__ unsigned short f2bf(float x) {
  unsigned u = __float_as_uint(x);
  u += 0x7FFFu + ((u >> 16) & 1u);            // RNE
  return (unsigned short)(u >> 16);
}
__device__ __forceinline__ float bf2f(unsigned short s) {
  return __uint_as_float(((unsigned)s) << 16);
}
__device__ __forceinline__ void split2(float v, short* hi, short* lo) {
  unsigned short h = f2bf(v);
  *hi = (short)h;
  *lo = (short)f2bf(v - bf2f(h));
}
__device__ __forceinline__ f32x4 mma_bf16(bf16x8 a, bf16x8 b, f32x4 c) {
  return __builtin_amdgcn_mfma_f32_16x16x32_bf16(a, b, c, 0, 0, 0);
}
__device__ __forceinline__ f32x4 mma_f16(f16x8 a, f16x8 b, f32x4 c) {
  return __builtin_amdgcn_mfma_f32_16x16x32_f16(a, b, c, 0, 0, 0);
}
// fast activations (rcp = v_rcp_f32, ~1ulp; safe at +-inf)
__device__ __forceinline__ float fast_sigmoid(float x) {
  return __builtin_amdgcn_rcpf(1.0f + __expf(-x));
}
__device__ __forceinline__ float fast_tanh(float x) {
  return 1.0f - 2.0f * __builtin_amdgcn_rcpf(1.0f + __expf(2.0f * x));
}

// write-through-to-LLC stores (LLC/MALL = chip-level coherence point)
__device__ __forceinline__ void st_sc32u(unsigned* p, unsigned v) {
  asm volatile("global_store_dword %0, %1, off sc0 sc1" :: "v"(p), "v"(v) : "memory");
}
__device__ __forceinline__ void st_sc128(void* p, i32x4 v) {
  asm volatile("global_store_dwordx4 %0, %1, off sc0 sc1" :: "v"(p), "v"(v) : "memory");
}
// non-temporal store for the logits stream
__device__ __forceinline__ void st_nt(float* p, float v) {
  asm volatile("global_store_dword %0, %1, off nt" :: "v"(p), "v"(v) : "memory");
}
// fresh MALL read, NON-atomic
__device__ __forceinline__ unsigned ld_sc32u(const unsigned* p) {
  unsigned v;
  asm volatile("global_load_dword %0, %1, off sc0 sc1\n\ts_waitcnt vmcnt(0)"
               : "=v"(v) : "v"(p) : "memory");
  return v;
}

// generic per-lane wait: every lane polls its own (fp, thr); one MALL txn per
// distinct line per iteration; exits when ALL lanes satisfied.
__device__ __forceinline__ void wave_poll(const unsigned* fp, unsigned thr) {
  while (!__all((int)(ld_sc32u(fp) >= thr))) {}
}
// per-wave poll of 4 producer flags: cg = cgBase + (lane&3)
__device__ __forceinline__ void wave_poll4(const unsigned* flags, int slotBase, int cgBase,
                                           int rh, unsigned thr, int lane) {
  const unsigned* fp = &flags[(size_t)(slotBase + (cgBase + (lane & 3)) * 2 + rh) * 32];
  wave_poll(fp, thr);
}

// Publish own flag after draining this wg's data stores.
__device__ __forceinline__ void publish(unsigned* flags, int slot, unsigned val) {
  asm volatile("s_waitcnt vmcnt(0)" ::: "memory");
  __syncthreads();
  if (threadIdx.x == 0) st_sc32u(&flags[(size_t)slot * 32], val);
}

// ---------------- prep ----------------
__global__ void k_prep(
    const float* __restrict__ outw, const int* __restrict__ toks,
    const float* __restrict__ emb, const float* __restrict__ hid,
    _Float16* OWf, short* XeHi, short* XeLo,
    short* X1Hi, short* X1Lo, short* h0Hi, short* h0Lo) {
  const size_t stride = (size_t)gridDim.x * blockDim.x;
  const size_t N1 = SZ_OW, N2 = N1 + SZ_XE, N3 = N2 + SZ_H, N4 = N3 + SZ_H;
  for (size_t x = (size_t)blockIdx.x * blockDim.x + threadIdx.x; x < N4; x += stride) {
    if (x < N1) {
      OWf[x] = (_Float16)outw[x];
    } else if (x < N2) {
      size_t p = x - N1;
      size_t r = p >> 9, c = p & 511u;
      int tok = toks[r];
      float v = emb[(size_t)tok * 512 + c];
      short hi, lo; split2(v, &hi, &lo);
      XeHi[p] = hi; XeLo[p] = lo;
    } else if (x < N3) {
      size_t p = x - N2;
      short hi, lo; split2(hid[p], &hi, &lo);
      h0Hi[p] = hi; h0Lo[p] = lo;
    } else {
      size_t p = x - N3;
      short hi, lo; split2(hid[SZ_H + p], &hi, &lo);
      X1Hi[p] = hi; X1Lo[p] = lo;
    }
  }
}

// ---------------- 32-row P-class MMA: one 512-k half, 4-way k-split ----------------
// wave = kq(0..3)*2 + rhalf(0..1); activation ptrs pre-offset by rowbase*512.
__device__ __forceinline__ void mmaP32(
    const short* __restrict__ aH, const short* __restrict__ aL, int base,
    const short* lsHi_, const short* lsLo_,
    f32x4 (&accH)[2], f32x4 (&accL)[2], int wave, int l15, int lq) {
  const int kq = wave >> 1, rhalf = wave & 1;
  const int r0 = rhalf * 16 + l15;
#pragma unroll
  for (int i = 0; i < 4; ++i) {
    const int ko = kq * 128 + i * 32 + lq * 8;
    const int kg = base + ko;
    const int e0 = (l15 * 1024 + kg) ^ ((l15 & 7) << 3);
    const int e1 = ((16 + l15) * 1024 + kg) ^ ((l15 & 7) << 3);
    bf16x8 bh0 = *(const bf16x8*)&lsHi_[e0];
    bf16x8 bl0 = *(const bf16x8*)&lsLo_[e0];
    bf16x8 bh1 = *(const bf16x8*)&lsHi_[e1];
    bf16x8 bl1 = *(const bf16x8*)&lsLo_[e1];
    bf16x8 ah = *(const bf16x8*)&aH[r0 * 512 + ko];
    bf16x8 al = *(const bf16x8*)&aL[r0 * 512 + ko];
    accH[0] = mma_bf16(ah, bh0, accH[0]);
    accH[1] = mma_bf16(ah, bh1, accH[1]);
    accL[0] = mma_bf16(al, bh0, accL[0]);
    accL[1] = mma_bf16(al, bh1, accL[1]);
    accL[0] = mma_bf16(ah, bl0, accL[0]);
    accL[1] = mma_bf16(ah, bl1, accL[1]);
  }
}
// 4-way cross-wave k-reduce; owners = waves 0,1 (kq=0, rhalf=wave).
__device__ __forceinline__ void reduce4(float* lsRed_, f32x4 (&accH)[2], f32x4 (&accL)[2],
                                        f32x4 (&acc)[2], int wave, int l15, int lq) {
  const int kq = wave >> 1, rhalf = wave & 1;
  acc[0] = accH[0] + accL[0];
  acc[1] = accH[1] + accL[1];
  const int pos = l15 * 16 + lq * 4;
  if (kq) {
    *(f32x4*)&lsRed_[(((kq - 1) * 2 + rhalf) * 2 + 0) * 256 + pos] = acc[0];
    *(f32x4*)&lsRed_[(((kq - 1) * 2 + rhalf) * 2 + 1) * 256 + pos] = acc[1];
  }
  __syncthreads();
  if (!kq) {
#pragma unroll
    for (int s = 0; s < 3; ++s) {
      acc[0] += *(const f32x4*)&lsRed_[((s * 2 + rhalf) * 2 + 0) * 256 + pos];
      acc[1] += *(const f32x4*)&lsRed_[((s * 2 + rhalf) * 2 + 1) * 256 + pos];
    }
  }
  __syncthreads();
}

// ---------------- l1A full-k MMA (32 rows) ----------------
__device__ __forceinline__ void mmaD(
    const short* __restrict__ pAH, const short* __restrict__ pAL,
    int kloc0, int kkGlob0, const short* lsHi_, const short* lsLo_,
    f32x4 (&accH)[2], f32x4 (&accL)[2], int l15, int lq, int rhalf, int rowbase) {
  const int r0 = rowbase + rhalf * 16 + l15;
#pragma unroll 4
  for (int i = 0; i < 8; ++i) {
    const int kk = kkGlob0 + i * 32 + lq * 8;
    const int ka = kloc0 + i * 32 + lq * 8;
    const int e0 = (l15 * 1024 + kk) ^ ((l15 & 7) << 3);
    const int e1 = ((16 + l15) * 1024 + kk) ^ ((l15 & 7) << 3);
    bf16x8 bh0 = *(const bf16x8*)&lsHi_[e0];
    bf16x8 bl0 = *(const bf16x8*)&lsLo_[e0];
    bf16x8 bh1 = *(const bf16x8*)&lsHi_[e1];
    bf16x8 bl1 = *(const bf16x8*)&lsLo_[e1];
    bf16x8 ah = *(const bf16x8*)&pAH[r0 * 512 + ka];
    bf16x8 al = *(const bf16x8*)&pAL[r0 * 512 + ka];
    accH[0] = mma_bf16(ah, bh0, accH[0]);
    accH[1] = mma_bf16(ah, bh1, accH[1]);
    accL[0] = mma_bf16(al, bh0, accL[0]);
    accL[1] = mma_bf16(al, bh1, accL[1]);
    accL[0] = mma_bf16(ah, bl0, accL[0]);
    accL[1] = mma_bf16(ah, bl1, accL[1]);
  }
}
// 8-wave reduce for the full-k path; owners waves 0,1.
__device__ __forceinline__ void reduceD(float* lsRed_, f32x4 (&accH)[2], f32x4 (&accL)[2],
                                        f32x4 (&acc)[2], int wave, int l15, int lq) {
  acc[0] = accH[0] + accL[0];
  acc[1] = accH[1] + accL[1];
  const int pos = l15 * 16 + lq * 4;
  if (wave >= 2) {
    *(f32x4*)&lsRed_[((wave - 2) * 2 + 0) * 256 + pos] = acc[0];
    *(f32x4*)&lsRed_[((wave - 2) * 2 + 1) * 256 + pos] = acc[1];
  }
  __syncthreads();
  if (wave < 2) {
#pragma unroll
    for (int s = 0; s < 3; ++s) {
      const int slot = (wave & 1) + 2 * s;
      acc[0] += *(const f32x4*)&lsRed_[(slot * 2 + 0) * 256 + pos];
      acc[1] += *(const f32x4*)&lsRed_[(slot * 2 + 1) * 256 + pos];
    }
  }
  __syncthreads();
}

// weight staging: 32 rows x 1024 k as split bf16 hi/lo, XOR-swizzled
__device__ __forceinline__ void stage_weights(
    short* lsHi, short* lsLo, const float* srcBase0, const float* srcBase1,
    int jc, int tid) {
  for (int i = tid; i < 8192; i += 512) {
    const int j = i >> 8;
    const int k4 = (i & 255) << 2;
    const int g = jc + j;
    const float* src = (srcBase1 && g >= 512)
        ? (srcBase1 + (size_t)(g - 512) * 1024 + k4)
        : (srcBase0 + (size_t)g * 1024 + k4);
    f32x4 v = *(const f32x4*)src;
    s16x4 h4, l4;
#pragma unroll
    for (int q = 0; q < 4; ++q) { short hi, lo; split2(v[q], &hi, &lo); h4[q] = hi; l4[q] = lo; }
    const int els = (j * 1024 + k4) ^ ((j & 7) << 3);
    *(s16x4*)&lsHi[els] = h4;
    *(s16x4*)&lsLo[els] = l4;
  }
}

// ---------------- shared GEMM loop: 256x256 quad steals ----------------
__device__ void gemm_loop(char* pool, int tid,
                          const _Float16* Af, const _Float16* Bw,
                          const float* bias, float* C,
                          unsigned* flags, unsigned* tcnt) {
  _Float16* lsA0 = (_Float16*)pool;            // 16 KB each
  _Float16* lsA1 = lsA0 + 8192;
  _Float16* lsB0 = lsA1 + 8192;
  _Float16* lsB1 = lsB0 + 8192;                // 64 KB total
  volatile int* bc = (volatile int*)(pool + 65536);
  const int wave = tid >> 6, lane = tid & 63, l15 = lane & 15, lq = lane >> 4;
  const int wr = (wave >> 2) * 64, wc = (wave & 3) * 32;
  unsigned lastR = 0;
  __syncthreads();
  for (;;) {
    if (tid == 0)
      *bc = (int)__hip_atomic_fetch_add(tcnt, 1u, __ATOMIC_RELAXED,
                                        __HIP_MEMORY_SCOPE_AGENT);
    __syncthreads();
    const int pr = *bc;
    __syncthreads();
    if (pr >= NQUAD) break;
    const int p = pr / 125, bq = pr - p * 125;
    const unsigned Rneed = 4u * (unsigned)p + 4u;   // X1f16 t up to 4p+3
    if (lastR < Rneed) {
      if (tid < 32) {
        const unsigned* fp = &flags[(size_t)(160 + tid) * 32];
        while (ld_sc32u(fp) < Rneed) __builtin_amdgcn_s_sleep(8);
      }
      lastR = Rneed;
    }
    __syncthreads();
    f32x4 a00[4][2] = {}, a01[4][2] = {}, a10[4][2] = {}, a11[4][2] = {};
    const size_t arow0 = (size_t)p * 256;
    const size_t brow0 = (size_t)bq * 256;
    for (int kb = 0; kb < 512; kb += 64) {
#pragma unroll
      for (int i = 0; i < 2; ++i) {
        int c = tid + i * 512;
        int row = c >> 3, kc = (c & 7) * 8;
        int el = (row * 64 + kc) ^ ((row & 7) << 3);
        *(f16x8*)&lsA0[el] = *(const f16x8*)(Af + (arow0 + row) * 512 + kb + kc);
        *(f16x8*)&lsA1[el] = *(const f16x8*)(Af + (arow0 + 128 + row) * 512 + kb + kc);
        *(f16x8*)&lsB0[el] = *(const f16x8*)(Bw + (brow0 + row) * 512 + kb + kc);
        *(f16x8*)&lsB1[el] = *(const f16x8*)(Bw + (brow0 + 128 + row) * 512 + kb + kc);
      }
      __syncthreads();
#pragma unroll
      for (int k0 = 0; k0 < 64; k0 += 32) {
        const int kk = k0 + lq * 8;
        f16x8 af0[4], af1[4], b0[2], b1[2];
#pragma unroll
        for (int i = 0; i < 4; ++i) {
          int ra = wr + i * 16 + l15;
          int el = (ra * 64 + kk) ^ ((ra & 7) << 3);
          af0[i] = *(const f16x8*)&lsA0[el];
          af1[i] = *(const f16x8*)&lsA1[el];
        }
#pragma unroll
        for (int jt = 0; jt < 2; ++jt) {
          int rb = wc + jt * 16 + l15;
          int el = (rb * 64 + kk) ^ ((rb & 7) << 3);
          b0[jt] = *(const f16x8*)&lsB0[el];
          b1[jt] = *(const f16x8*)&lsB1[el];
        }
#pragma unroll
        for (int i = 0; i < 4; ++i)
#pragma unroll
          for (int jt = 0; jt < 2; ++jt) {
            a00[i][jt] = mma_f16(af0[i], b0[jt], a00[i][jt]);
            a01[i][jt] = mma_f16(af0[i], b1[jt], a01[i][jt]);
            a10[i][jt] = mma_f16(af1[i], b0[jt], a10[i][jt]);
            a11[i][jt] = mma_f16(af1[i], b1[jt], a11[i][jt]);
          }
      }
      __syncthreads();
    }
    // line-merged epilogue for all 4 tiles
    const float c00 = bias[brow0 + wc + l15];
    const float c01 = bias[brow0 + wc + 16 + l15];
    const float c10 = bias[brow0 + 128 + wc + l15];
    const float c11 = bias[brow0 + 128 + wc + 16 + l15];
#pragma unroll
    for (int i = 0; i < 4; ++i) {
#pragma unroll
      for (int r = 0; r < 4; ++r) {
        const size_t row = arow0 + wr + i * 16 + lq * 4 + r;
        float* pa = C + row * (size_t)NV + brow0 + wc + l15;
        st_nt(pa, a00[i][0][r] + c00);
        st_nt(pa + 16, a00[i][1][r] + c01);
        st_nt(pa + 128, a01[i][0][r] + c10);
        st_nt(pa + 144, a01[i][1][r] + c11);
        float* pb = pa + (size_t)128 * NV;
        st_nt(pb, a10[i][0][r] + c00);
        st_nt(pb + 16, a10[i][1][r] + c01);
        st_nt(pb + 128, a11[i][0][r] + c10);
        st_nt(pb + 144, a11[i][1][r] + c11);
      }
    }
  }
}

// ================= fused persistent kernel =================
__launch_bounds__(512, 1)
__global__ void k_main(
    const float* __restrict__ Wr, const float* __restrict__ Wz, const float* __restrict__ Wh,
    const float* __restrict__ Wrb, const float* __restrict__ Wzb, const float* __restrict__ Whb,
    const short* __restrict__ XeHi, const short* __restrict__ XeLo,
    short* X1Hi, short* X1Lo, _Float16* X1f16,
    short* h0Hi, short* h0Lo,
    short* rh0Hi, short* rh0Lo, short* rh1Hi, short* rh1Lo,
    float* z0, float* z1, float* hidOut,
    const _Float16* OWf, const float* outb, float* out,
    unsigned* flags, unsigned* tcnt) {
  __shared__ __align__(16) char pool[153600];
  short* lsHi = (short*)pool;                  // 64 KB weights hi
  short* lsLo = lsHi + 32 * 1024;              // 64 KB weights lo
  float* lsRed = (float*)(pool + 131072);      // 12 KB reduce scratch
  short* sH    = (short*)(pool + 131072);      // epilogue overlay (post-reduce)
  short* sL    = sH + 1024;
  float* sZA   = (float*)(pool + 131072);
  short* stH   = (short*)(pool + 143360);      // 2 KB prestage hi
  short* stL   = stH + 1024;                   // 2 KB prestage lo
  float* sZ    = (float*)(pool + 147456);      // 4 KB z prestage
  _Float16* sX = (_Float16*)(pool + 151552);   // 2 KB X1f16 stage

  const int wg = blockIdx.x;
  const int tid = threadIdx.x;
  const int wave = tid >> 6, lane = tid & 63, l15 = lane & 15, lq = lane >> 4;

  if (wg < 64) {
    // ===== l0A: layer-0 gates, 32 cols x 32 rows =====
    const int cg = wg >> 1, rh = wg & 1, jc = cg * 32, rowbase = rh * 32;
    const bool isR = (jc < 512);
    stage_weights(lsHi, lsLo, Wr, Wz, jc, tid);
    float biasL0, biasL1;
    {
      const int j0 = jc + l15, j1 = j0 + 16;
      biasL0 = (j0 < 512) ? Wrb[j0] : Wzb[j0 - 512];
      biasL1 = (j1 < 512) ? Wrb[j1] : Wzb[j1 - 512];
    }
    __syncthreads();
    for (int t = 0; t < NT; ++t) {
      f32x4 accH[2] = {}, accL[2] = {};
      mmaP32(XeHi + (size_t)t * SZ_H + rowbase * 512,
             XeLo + (size_t)t * SZ_H + rowbase * 512, 0,
             lsHi, lsLo, accH, accL, wave, l15, lq);   // static x-half (no deps)
      const short* hH = h0Hi + (size_t)t * SZ_H + rowbase * 512;
      const short* hL = h0Lo + (size_t)t * SZ_H + rowbase * 512;
      // MERGED wait: lanes 0-3 = slice producers; lane 4 = prestage producer
      {
        const int idx = lane & 7;
        int cgp = 4 * (wave >> 1) + (idx & 3);
        if (idx == 4 && isR) cgp = (jc >> 5);
        const unsigned* fp = &flags[(size_t)(128 + cgp * 2 + rh) * 32];
        wave_poll(fp, (unsigned)t);
      }
      // register-carried prestage (producer already confirmed by merged wait)
      i32x4 pre;
      const int pbuf = tid >> 7, pq = tid & 127, prow = pq >> 2, pc = pq & 3;
      if (isR && tid < 256)
        pre = *(const i32x4*)((pbuf ? hL : hH) + prow * 512 + jc + pc * 8);
      mmaP32(hH, hL, 512, lsHi, lsLo, accH, accL, wave, l15, lq);  // dependent h-half
      if (isR && tid < 256)
        *(i32x4*)&(pbuf ? stL : stH)[prow * 32 + pc * 8] = pre;
      f32x4 acc[2];
      reduce4(lsRed, accH, accL, acc, wave, l15, lq);
      if (wave < 2) {
#pragma unroll
        for (int ct = 0; ct < 2; ++ct) {
          const int jj = ct * 16 + l15;
          const float bv = ct ? biasL1 : biasL0;
#pragma unroll
          for (int r = 0; r < 4; ++r) {
            const int lb = wave * 16 + lq * 4 + r;
            const float s = fast_sigmoid(acc[ct][r] + bv);
            if (isR) {
              const float hv = bf2f((unsigned short)stH[lb * 32 + jj]) +
                               bf2f((unsigned short)stL[lb * 32 + jj]);
              short hi, lo; split2(s * hv, &hi, &lo);
              sH[lb * 32 + jj] = hi; sL[lb * 32 + jj] = lo;
            } else {
              sZA[lb * 32 + jj] = s;
            }
          }
        }
      }
      __syncthreads();
      if (isR) {
        if (tid < 256) {
          i32x4 v = *(const i32x4*)&(pbuf ? sL : sH)[prow * 32 + pc * 8];
          st_sc128((pbuf ? rh0Lo : rh0Hi) + (size_t)t * SZ_H +
                   (size_t)(rowbase + prow) * 512 + jc + pc * 8, v);
        }
      } else {
        if (tid < 256) {
          const int row = tid >> 3, c = tid & 7;
          i32x4 v = *(const i32x4*)&sZA[row * 32 + c * 4];
          st_sc128(z0 + (size_t)t * SZ_H + (size_t)(rowbase + row) * 512 +
                   (jc - 512) + c * 4, v);
        }
      }
      publish(flags, wg, (unsigned)(t + 1));
    }
  } else if (wg < 128) {
    // ===== l1A: layer-1 gates, 32 cols x 32 rows, full-k (per-wave dataflow) =====
    const int idx0 = wg - 64, cg = idx0 >> 1, rh = idx0 & 1, jc = cg * 32, rowbase = (idx0 & 1) * 32;
    const bool isR = (jc < 512);
    stage_weights(lsHi, lsLo, Wr + (size_t)512 * 1024, Wz + (size_t)512 * 1024, jc, tid);
    float biasL0, biasL1;
    {
      const int j0 = jc + l15, j1 = j0 + 16;
      biasL0 = (j0 < 512) ? Wrb[512 + j0] : Wzb[512 + j0 - 512];
      biasL1 = (j1 < 512) ? Wrb[512 + j1] : Wzb[512 + j1 - 512];
    }
    __syncthreads();
    for (int t = 0; t < NT; ++t) {
      const short* xH = h0Hi + (size_t)(t + 1) * SZ_H;
      const short* xL = h0Lo + (size_t)(t + 1) * SZ_H;
      const short* hH = X1Hi + (size_t)t * SZ_H;
      const short* hL = X1Lo + (size_t)t * SZ_H;
      // MERGED per-wave wait: lanes 0-7 = this khalf's 8 slice producers;
      // lane 8 = prestage producer (l1B cg=jc>>5, thr t)
      const int khalf = wave >> 1, rhalf = wave & 1;
      {
        const int idx = lane & 15;
        const unsigned* fp; unsigned thr;
        if (idx == 8 && isR) {
          fp = &flags[(size_t)(160 + (jc >> 5) * 2 + rh) * 32]; thr = (unsigned)t;
        } else if (khalf < 2) {
          const int cgp = (khalf & 1) * 8 + (idx & 7);
          fp = &flags[(size_t)(128 + cgp * 2 + rh) * 32]; thr = (unsigned)(t + 1);
        } else {
          const int cgp = (khalf & 1) * 8 + (idx & 7);
          fp = &flags[(size_t)(160 + cgp * 2 + rh) * 32]; thr = (unsigned)t;
        }
        wave_poll(fp, thr);
      }
      // register-carried prestage (producer confirmed)
      i32x4 pre;
      const int pbuf = tid >> 7, pq = tid & 127, prow = pq >> 2, pc = pq & 3;
      if (isR && tid < 256)
        pre = *(const i32x4*)((pbuf ? hL : hH) +
                              (size_t)(rowbase + prow) * 512 + jc + pc * 8);
      f32x4 accH[2] = {}, accL[2] = {};
      {
        const short* pAH = (khalf < 2) ? xH : hH;
        const short* pAL = (khalf < 2) ? xL : hL;
        mmaD(pAH, pAL, (khalf & 1) * 256, khalf * 256, lsHi, lsLo,
             accH, accL, l15, lq, rhalf, rowbase);
      }
      if (isR && tid < 256)
        *(i32x4*)&(pbuf ? stL : stH)[prow * 32 + pc * 8] = pre;
      f32x4 acc[2];
      reduceD(lsRed, accH, accL, acc, wave, l15, lq);
      if (wave < 2) {
#pragma unroll
        for (int ct = 0; ct < 2; ++ct) {
          const int jj = ct * 16 + l15;
          const float bv = ct ? biasL1 : biasL0;
#pragma unroll
          for (int r = 0; r < 4; ++r) {
            const int lb = wave * 16 + lq * 4 + r;
            const float s = fast_sigmoid(acc[ct][r] + bv);
            if (isR) {
              const float hv = bf2f((unsigned short)stH[lb * 32 + jj]) +
                               bf2f((unsigned short)stL[lb * 32 + jj]);
              short hi, lo; split2(s * hv, &hi, &lo);
              sH[lb * 32 + jj] = hi; sL[lb * 32 + jj] = lo;
            } else {
              sZA[lb * 32 + jj] = s;
            }
          }
        }
      }
      __syncthreads();
      if (isR) {
        if (tid < 256) {
          i32x4 v = *(const i32x4*)&(pbuf ? sL : sH)[prow * 32 + pc * 8];
          st_sc128((pbuf ? rh1Lo : rh1Hi) + (size_t)t * SZ_H +
                   (size_t)(rowbase + prow) * 512 + jc + pc * 8, v);
        }
      } else {
        if (tid < 256) {
          const int row = tid >> 3, c = tid & 7;
          i32x4 v = *(const i32x4*)&sZA[row * 32 + c * 4];
          st_sc128(z1 + (size_t)t * SZ_H + (size_t)(rowbase + row) * 512 +
                   (jc - 512) + c * 4, v);
        }
      }
      publish(flags, wg, (unsigned)(t + 1));
    }
  } else if (wg < 192) {
    // ===== B classes: candidate + state, 32 cols x 32 rows (per-wave dataflow) =====
    const bool isL1 = (wg >= 160);
    const int idx0 = isL1 ? (wg - 160) : (wg - 128);
    const int cg = idx0 >> 1, rh = idx0 & 1, jc = cg * 32, rowbase = (idx0 & 1) * 32;
    const int layer = isL1 ? 1 : 0;
    stage_weights(lsHi, lsLo, Wh + (size_t)layer * 512 * 1024, nullptr, jc, tid);
    const float biasL0 = Whb[layer * 512 + jc + l15];
    const float biasL1 = Whb[layer * 512 + jc + 16 + l15];
    __syncthreads();
    short* myHi = isL1 ? X1Hi : h0Hi;
    short* myLo = isL1 ? X1Lo : h0Lo;
    const short* rhHi_ = isL1 ? rh1Hi : rh0Hi;
    const short* rhLo_ = isL1 ? rh1Lo : rh0Lo;
    const float* zArr = isL1 ? z1 : z0;
    const int fbase = isL1 ? 64 : 0;    // A-class flag base for this layer
    for (int t = 0; t < NT; ++t) {
      // prestage own hOld (self-produced, no wait)
      const int pbuf = tid >> 7, pq = tid & 127, prow = pq >> 2, pc = pq & 3;
      if (tid < 256) {
        const short* src = (pbuf ? myLo : myHi) + (size_t)t * SZ_H +
                           (size_t)(rowbase + prow) * 512 + jc + pc * 8;
        *(i32x4*)&(pbuf ? stL : stH)[prow * 32 + pc * 8] = *(const i32x4*)src;
      }
      f32x4 accH[2] = {}, accL[2] = {};
      if (isL1) {
        // x1(t)=h0(t+1): per-wave 4 l0B producers >= t+1
        wave_poll4(flags, 128, 4 * (wave >> 1), rh, (unsigned)(t + 1), lane);
        mmaP32(h0Hi + (size_t)(t + 1) * SZ_H + rowbase * 512,
               h0Lo + (size_t)(t + 1) * SZ_H + rowbase * 512, 0,
               lsHi, lsLo, accH, accL, wave, l15, lq);
      } else {
        mmaP32(XeHi + (size_t)t * SZ_H + rowbase * 512,
               XeLo + (size_t)t * SZ_H + rowbase * 512, 0,
               lsHi, lsLo, accH, accL, wave, l15, lq);   // static x-half
      }
      // MERGED wait: lanes 0-3 = rh slice producers; lane 4 = z producer (same thr)
      {
        const int idx = lane & 7;
        int cgp = 4 * (wave >> 1) + (idx & 3);
        if (idx == 4) cgp = 16 + (jc >> 5);
        const unsigned* fp = &flags[(size_t)(fbase + cgp * 2 + rh) * 32];
        wave_poll(fp, (unsigned)(t + 1));
      }
      // register-carried z-stage (producer confirmed)
      f32x4 zv;
      const int zrow = tid >> 3, zc = tid & 7;
      if (tid < 256)
        zv = *(const f32x4*)(zArr + (size_t)t * SZ_H +
                             (size_t)(rowbase + zrow) * 512 + jc + zc * 4);
      mmaP32(rhHi_ + (size_t)t * SZ_H + rowbase * 512,
             rhLo_ + (size_t)t * SZ_H + rowbase * 512, 512,
             lsHi, lsLo, accH, accL, wave, l15, lq);     // dependent rh-half
      if (tid < 256)
        *(f32x4*)&sZ[zrow * 32 + zc * 4] = zv;
      f32x4 acc[2];
      reduce4(lsRed, accH, accL, acc, wave, l15, lq);
      if (wave < 2) {
#pragma unroll
        for (int ct = 0; ct < 2; ++ct) {
          const int jj = ct * 16 + l15, j = jc + jj;
          const float bv = ct ? biasL1 : biasL0;
#pragma unroll
          for (int r = 0; r < 4; ++r) {
            const int lb = wave * 16 + lq * 4 + r;
            const float hh = fast_tanh(acc[ct][r] + bv);
            const float z = sZ[lb * 32 + jj];
            const float ho = bf2f((unsigned short)stH[lb * 32 + jj]) +
                             bf2f((unsigned short)stL[lb * 32 + jj]);
            const float hn = (1.0f - z) * ho + z * hh;
            short hi, lo; split2(hn, &hi, &lo);
            sH[lb * 32 + jj] = hi; sL[lb * 32 + jj] = lo;
            if (isL1) sX[lb * 32 + jj] = (_Float16)hn;
            if (t == NT - 1)
              hidOut[(size_t)layer * SZ_H + (size_t)(rowbase + lb) * 512 + j] = hn;
          }
        }
      }
      __syncthreads();
      if (tid < 256) {
        i32x4 v = *(const i32x4*)&(pbuf ? sL : sH)[prow * 32 + pc * 8];
        st_sc128((pbuf ? myLo : myHi) + (size_t)(t + 1) * SZ_H +
                 (size_t)(rowbase + prow) * 512 + jc + pc * 8, v);
      } else if (isL1 && tid < 384) {
        const int q = tid - 256, row = q >> 2, c = q & 3;
        i32x4 v = *(const i32x4*)&sX[row * 32 + c * 8];
        st_sc128(X1f16 + (size_t)t * SZ_H + (size_t)(rowbase + row) * 512 + jc + c * 8, v);
      }
      publish(flags, wg, (unsigned)(t + 1));
    }
  }
  // ===== everyone converges on the GEMM (dedicated wgs 192..255 start now) =====
  gemm_loop(pool, tid, X1f16, OWf, outb, out, flags, tcnt);
}

// ---------------- launcher ----------------
extern "C" void kernel_launch(void* const* d_in, const int* in_sizes, int n_in,
                              void* d_out, int out_size, void* d_ws, size_t ws_size,
                              hipStream_t stream) {
  (void)in_sizes; (void)n_in; (void)out_size; (void)ws_size;
  const int*   toks = (const int*)d_in[0];
  const float* hid  = (const float*)d_in[1];
  const float* emb  = (const float*)d_in[2];
  const float* Wr   = (const float*)d_in[3];
  const float* Wrb  = (const float*)d_in[4];
  const float* Wz   = (const float*)d_in[5];
  const float* Wzb  = (const float*)d_in[6];
  const float* Wh   = (const float*)d_in[7];
  const float* Whb  = (const float*)d_in[8];
  const float* outw = (const float*)d_in[9];
  const float* outb = (const float*)d_in[10];
  float* out = (float*)d_out;

  char* base = (char*)d_ws;
  size_t off = 0;
  auto carve = [&](size_t bytes) -> char* {
    char* r = base + off;
    off = (off + bytes + 255) & ~(size_t)255;
    return r;
  };
  _Float16* OWf   = (_Float16*)carve(SZ_OW * 2);
  short*    XeHi  = (short*)carve(SZ_XE * 2);
  short*    XeLo  = (short*)carve(SZ_XE * 2);
  short*    X1Hi  = (short*)carve((size_t)(NT + 1) * SZ_H * 2);
  short*    X1Lo  = (short*)carve((size_t)(NT + 1) * SZ_H * 2);
  _Float16* X1f16 = (_Float16*)carve((size_t)NT * SZ_H * 2);
  short*    h0Hi  = (short*)carve((size_t)(NT + 1) * SZ_H * 2);
  short*    h0Lo  = (short*)carve((size_t)(NT + 1) * SZ_H * 2);
  short*    rh0Hi = (short*)carve((size_t)NT * SZ_H * 2);
  short*    rh0Lo = (short*)carve((size_t)NT * SZ_H * 2);
  short*    rh1Hi = (short*)carve((size_t)NT * SZ_H * 2);
  short*    rh1Lo = (short*)carve((size_t)NT * SZ_H * 2);
  float*    z0    = (float*)carve((size_t)NT * SZ_H * 4);
  float*    z1    = (float*)carve((size_t)NT * SZ_H * 4);
  unsigned* flags = (unsigned*)carve(32768);   // 192 slots * 128B
  unsigned* tcnt  = (unsigned*)carve(256);

  hipMemsetAsync(flags, 0, 32768, stream);
  hipMemsetAsync(tcnt, 0, 256, stream);

  k_prep<<<2048, 256, 0, stream>>>(outw, toks, emb, hid,
                                   OWf, XeHi, XeLo, X1Hi, X1Lo, h0Hi, h0Lo);

  k_main<<<256, 512, 0, stream>>>(
      Wr, Wz, Wh, Wrb, Wzb, Whb, XeHi, XeLo,
      X1Hi, X1Lo, X1f16, h0Hi, h0Lo,
      rh0Hi, rh0Lo, rh1Hi, rh1Lo, z0, z1,
      out + LOGITS, OWf, outb, out, flags, tcnt);
}

// Round 14
// 696.977 us; speedup vs baseline: 1.0089x; 1.0089x over previous
//
#include <hip/hip_runtime.h>

// ---------------- constants ----------------
constexpr int NT = 64;     // timesteps
constexpr int NB = 64;     // batch
constexpr int NV = 32000;  // vocab
constexpr int NE = 512;    // embed
constexpr int NH = 512;    // hidden
// wg classes: [0,64) l0A | [64,128) l1A | [128,160) l0B | [160,192) l1B | [192,256) gemm
constexpr int NPAIR = 16 * 250;   // gemm steals: (bm-pair, bn) -- 256-row A per steal

constexpr size_t SZ_OW  = (size_t)NV * NE;
constexpr size_t SZ_XE  = (size_t)NT * NB * NE;
constexpr size_t SZ_H   = (size_t)NB * NH;
constexpr size_t LOGITS = (size_t)NT * NB * NV;

typedef float f32x4 __attribute__((ext_vector_type(4)));
typedef int   i32x4 __attribute__((ext_vector_type(4)));
typedef short bf16x8 __attribute__((ext_vector_type(8)));
typedef short s16x4 __attribute__((ext_vector_type(4)));
typedef _Float16 f16x8 __attribute__((ext_vector_type(8)));

// ---------------- helpers ----------------
__device__ __forceinline__ unsigned short f2bf(float x) {
  unsigned u = __float_as_uint(x);
  u += 0x7FFFu + ((u >> 16) & 1u);            // RNE
  return (unsigned short)(u >> 16);
}
__device__ __forceinline__ float bf2f(unsigned short s) {
  return __uint_as_float(((unsigned)s) << 16);
}
__device__ __forceinline__ void split2(float v, short* hi, short* lo) {
  unsigned short h = f2bf(v);
  *hi = (short)h;
  *lo = (short)f2bf(v - bf2f(h));
}
__device__ __forceinline__ f32x4 mma_bf16(bf16x8 a, bf16x8 b, f32x4 c) {
  return __builtin_amdgcn_mfma_f32_16x16x32_bf16(a, b, c, 0, 0, 0);
}
__device__ __forceinline__ f32x4 mma_f16(f16x8 a, f16x8 b, f32x4 c) {
  return __builtin_amdgcn_mfma_f32_16x16x32_f16(a, b, c, 0, 0, 0);
}
// fast activations (rcp = v_rcp_f32, ~1ulp; safe at +-inf)
__device__ __forceinline__ float fast_sigmoid(float x) {
  return __builtin_amdgcn_rcpf(1.0f + __expf(-x));
}
__device__ __forceinline__ float fast_tanh(float x) {
  return 1.0f - 2.0f * __builtin_amdgcn_rcpf(1.0f + __expf(2.0f * x));
}

// write-through-to-LLC stores (LLC/MALL = chip-level coherence point)
__device__ __forceinline__ void st_sc32u(unsigned* p, unsigned v) {
  asm volatile("global_store_dword %0, %1, off sc0 sc1" :: "v"(p), "v"(v) : "memory");
}
__device__ __forceinline__ void st_sc128(void* p, i32x4 v) {
  asm volatile("global_store_dwordx4 %0, %1, off sc0 sc1" :: "v"(p), "v"(v) : "memory");
}
// non-temporal store for the logits stream
__device__ __forceinline__ void st_nt(float* p, float v) {
  asm volatile("global_store_dword %0, %1, off nt" :: "v"(p), "v"(v) : "memory");
}
// fresh MALL read, NON-atomic
__device__ __forceinline__ unsigned ld_sc32u(const unsigned* p) {
  unsigned v;
  asm volatile("global_load_dword %0, %1, off sc0 sc1\n\ts_waitcnt vmcnt(0)"
               : "=v"(v) : "v"(p) : "memory");
  return v;
}

// generic per-lane wait: every lane polls its own (fp, thr).
__device__ __forceinline__ void wave_poll(const unsigned* fp, unsigned thr) {
  while (!__all((int)(ld_sc32u(fp) >= thr))) {}
}
// per-wave poll of 4 producer flags: cg = cgBase + (lane&3)
__device__ __forceinline__ void wave_poll4(const unsigned* flags, int slotBase, int cgBase,
                                           int rh, unsigned thr, int lane) {
  const unsigned* fp = &flags[(size_t)(slotBase + (cgBase + (lane & 3)) * 2 + rh) * 32];
  wave_poll(fp, thr);
}

// Publish own flag after draining this wg's data stores.
__device__ __forceinline__ void publish(unsigned* flags, int slot, unsigned val) {
  asm volatile("s_waitcnt vmcnt(0)" ::: "memory");
  __syncthreads();
  if (threadIdx.x == 0) st_sc32u(&flags[(size_t)slot * 32], val);
}

// ---------------- prep ----------------
__global__ void k_prep(
    const float* __restrict__ outw, const int* __restrict__ toks,
    const float* __restrict__ emb, const float* __restrict__ hid,
    _Float16* OWf, short* XeHi, short* XeLo,
    short* X1Hi, short* X1Lo, short* h0Hi, short* h0Lo) {
  const size_t stride = (size_t)gridDim.x * blockDim.x;
  const size_t N1 = SZ_OW, N2 = N1 + SZ_XE, N3 = N2 + SZ_H, N4 = N3 + SZ_H;
  for (size_t x = (size_t)blockIdx.x * blockDim.x + threadIdx.x; x < N4; x += stride) {
    if (x < N1) {
      OWf[x] = (_Float16)outw[x];
    } else if (x < N2) {
      size_t p = x - N1;
      size_t r = p >> 9, c = p & 511u;
      int tok = toks[r];
      float v = emb[(size_t)tok * 512 + c];
      short hi, lo; split2(v, &hi, &lo);
      XeHi[p] = hi; XeLo[p] = lo;
    } else if (x < N3) {
      size_t p = x - N2;
      short hi, lo; split2(hid[p], &hi, &lo);
      h0Hi[p] = hi; h0Lo[p] = lo;
    } else {
      size_t p = x - N3;
      short hi, lo; split2(hid[SZ_H + p], &hi, &lo);
      X1Hi[p] = hi; X1Lo[p] = lo;
    }
  }
}

// ---------------- 32-row P-class MMA: one 512-k half, 4-way k-split ----------------
// EXPLICIT load-all-then-MMA: all 8 activation vectors issue before any MFMA,
// guaranteeing a single LLC round-trip for the dependent half.
__device__ __forceinline__ void mmaP32(
    const short* __restrict__ aH, const short* __restrict__ aL, int base,
    const short* lsHi_, const short* lsLo_,
    f32x4 (&accH)[2], f32x4 (&accL)[2], int wave, int l15, int lq) {
  const int kq = wave >> 1, rhalf = wave & 1;
  const int r0 = rhalf * 16 + l15;
  bf16x8 ah[4], al[4];
#pragma unroll
  for (int i = 0; i < 4; ++i) {
    const int ko = kq * 128 + i * 32 + lq * 8;
    ah[i] = *(const bf16x8*)&aH[r0 * 512 + ko];
    al[i] = *(const bf16x8*)&aL[r0 * 512 + ko];
  }
#pragma unroll
  for (int i = 0; i < 4; ++i) {
    const int kg = base + kq * 128 + i * 32 + lq * 8;
    const int e0 = (l15 * 1024 + kg) ^ ((l15 & 7) << 3);
    const int e1 = ((16 + l15) * 1024 + kg) ^ ((l15 & 7) << 3);
    bf16x8 bh0 = *(const bf16x8*)&lsHi_[e0];
    bf16x8 bl0 = *(const bf16x8*)&lsLo_[e0];
    bf16x8 bh1 = *(const bf16x8*)&lsHi_[e1];
    bf16x8 bl1 = *(const bf16x8*)&lsLo_[e1];
    accH[0] = mma_bf16(ah[i], bh0, accH[0]);
    accH[1] = mma_bf16(ah[i], bh1, accH[1]);
    accL[0] = mma_bf16(al[i], bh0, accL[0]);
    accL[1] = mma_bf16(al[i], bh1, accL[1]);
    accL[0] = mma_bf16(ah[i], bl0, accL[0]);
    accL[1] = mma_bf16(ah[i], bl1, accL[1]);
  }
}
// 4-way cross-wave k-reduce; owners = waves 0,1 (kq=0, rhalf=wave).
__device__ __forceinline__ void reduce4(float* lsRed_, f32x4 (&accH)[2], f32x4 (&accL)[2],
                                        f32x4 (&acc)[2], int wave, int l15, int lq) {
  const int kq = wave >> 1, rhalf = wave & 1;
  acc[0] = accH[0] + accL[0];
  acc[1] = accH[1] + accL[1];
  const int pos = l15 * 16 + lq * 4;
  if (kq) {
    *(f32x4*)&lsRed_[(((kq - 1) * 2 + rhalf) * 2 + 0) * 256 + pos] = acc[0];
    *(f32x4*)&lsRed_[(((kq - 1) * 2 + rhalf) * 2 + 1) * 256 + pos] = acc[1];
  }
  __syncthreads();
  if (!kq) {
#pragma unroll
    for (int s = 0; s < 3; ++s) {
      acc[0] += *(const f32x4*)&lsRed_[((s * 2 + rhalf) * 2 + 0) * 256 + pos];
      acc[1] += *(const f32x4*)&lsRed_[((s * 2 + rhalf) * 2 + 1) * 256 + pos];
    }
  }
  __syncthreads();
}

// ---------------- l1A full-k MMA (32 rows), loads hoisted in 2 batches ----------------
__device__ __forceinline__ void mmaD(
    const short* __restrict__ pAH, const short* __restrict__ pAL,
    int kloc0, int kkGlob0, const short* lsHi_, const short* lsLo_,
    f32x4 (&accH)[2], f32x4 (&accL)[2], int l15, int lq, int rhalf, int rowbase) {
  const int r0 = rowbase + rhalf * 16 + l15;
#pragma unroll
  for (int b = 0; b < 2; ++b) {
    bf16x8 ah[4], al[4];
#pragma unroll
    for (int i = 0; i < 4; ++i) {
      const int ka = kloc0 + (b * 4 + i) * 32 + lq * 8;
      ah[i] = *(const bf16x8*)&pAH[r0 * 512 + ka];
      al[i] = *(const bf16x8*)&pAL[r0 * 512 + ka];
    }
#pragma unroll
    for (int i = 0; i < 4; ++i) {
      const int kk = kkGlob0 + (b * 4 + i) * 32 + lq * 8;
      const int e0 = (l15 * 1024 + kk) ^ ((l15 & 7) << 3);
      const int e1 = ((16 + l15) * 1024 + kk) ^ ((l15 & 7) << 3);
      bf16x8 bh0 = *(const bf16x8*)&lsHi_[e0];
      bf16x8 bl0 = *(const bf16x8*)&lsLo_[e0];
      bf16x8 bh1 = *(const bf16x8*)&lsHi_[e1];
      bf16x8 bl1 = *(const bf16x8*)&lsLo_[e1];
      accH[0] = mma_bf16(ah[i], bh0, accH[0]);
      accH[1] = mma_bf16(ah[i], bh1, accH[1]);
      accL[0] = mma_bf16(al[i], bh0, accL[0]);
      accL[1] = mma_bf16(al[i], bh1, accL[1]);
      accL[0] = mma_bf16(ah[i], bl0, accL[0]);
      accL[1] = mma_bf16(ah[i], bl1, accL[1]);
    }
  }
}
// 8-wave reduce for the full-k path; owners waves 0,1.
__device__ __forceinline__ void reduceD(float* lsRed_, f32x4 (&accH)[2], f32x4 (&accL)[2],
                                        f32x4 (&acc)[2], int wave, int l15, int lq) {
  acc[0] = accH[0] + accL[0];
  acc[1] = accH[1] + accL[1];
  const int pos = l15 * 16 + lq * 4;
  if (wave >= 2) {
    *(f32x4*)&lsRed_[((wave - 2) * 2 + 0) * 256 + pos] = acc[0];
    *(f32x4*)&lsRed_[((wave - 2) * 2 + 1) * 256 + pos] = acc[1];
  }
  __syncthreads();
  if (wave < 2) {
#pragma unroll
    for (int s = 0; s < 3; ++s) {
      const int slot = (wave & 1) + 2 * s;
      acc[0] += *(const f32x4*)&lsRed_[(slot * 2 + 0) * 256 + pos];
      acc[1] += *(const f32x4*)&lsRed_[(slot * 2 + 1) * 256 + pos];
    }
  }
  __syncthreads();
}

// weight staging: 32 rows x 1024 k as split bf16 hi/lo, XOR-swizzled
__device__ __forceinline__ void stage_weights(
    short* lsHi, short* lsLo, const float* srcBase0, const float* srcBase1,
    int jc, int tid) {
  for (int i = tid; i < 8192; i += 512) {
    const int j = i >> 8;
    const int k4 = (i & 255) << 2;
    const int g = jc + j;
    const float* src = (srcBase1 && g >= 512)
        ? (srcBase1 + (size_t)(g - 512) * 1024 + k4)
        : (srcBase0 + (size_t)g * 1024 + k4);
    f32x4 v = *(const f32x4*)src;
    s16x4 h4, l4;
#pragma unroll
    for (int q = 0; q < 4; ++q) { short hi, lo; split2(v[q], &hi, &lo); h4[q] = hi; l4[q] = lo; }
    const int els = (j * 1024 + k4) ^ ((j & 7) << 3);
    *(s16x4*)&lsHi[els] = h4;
    *(s16x4*)&lsLo[els] = l4;
  }
}

// ---------------- shared GEMM loop: bm-pair stealing, line-merged epilogue ----------
__device__ void gemm_loop(char* pool, int tid,
                          const _Float16* Af, const _Float16* Bw,
                          const float* bias, float* C,
                          unsigned* flags, unsigned* tcnt) {
  _Float16* lsA0 = (_Float16*)pool;            // 16 KB (strip bm=2p)
  _Float16* lsA1 = lsA0 + 128 * 64;            // 16 KB (strip bm=2p+1)
  _Float16* lsB  = lsA1 + 128 * 64;            // 16 KB
  volatile int* bc = (volatile int*)(pool + 49152);
  const int wave = tid >> 6, lane = tid & 63, l15 = lane & 15, lq = lane >> 4;
  const int wr = (wave >> 2) * 64, wc = (wave & 3) * 32;
  unsigned lastR = 0;
  __syncthreads();
  for (;;) {
    if (tid == 0)
      *bc = (int)__hip_atomic_fetch_add(tcnt, 1u, __ATOMIC_RELAXED,
                                        __HIP_MEMORY_SCOPE_AGENT);
    __syncthreads();
    const int pr = *bc;
    __syncthreads();
    if (pr >= NPAIR) break;
    const int p = pr / 250, bn = pr - p * 250;
    const unsigned Rneed = 4u * (unsigned)p + 4u;   // X1f16 t up to 4p+3
    if (lastR < Rneed) {
      if (tid < 32) {
        const unsigned* fp = &flags[(size_t)(160 + tid) * 32];
        while (ld_sc32u(fp) < Rneed) __builtin_amdgcn_s_sleep(8);
      }
      lastR = Rneed;
    }
    __syncthreads();
    f32x4 acc0[4][2] = {}, acc1[4][2] = {};
    const size_t arow0 = (size_t)p * 256;
    const size_t brow0 = (size_t)bn * 128;
    for (int kb = 0; kb < 512; kb += 64) {
#pragma unroll
      for (int i = 0; i < 2; ++i) {
        int c = tid + i * 512;
        int row = c >> 3, kc = (c & 7) * 8;
        int el = (row * 64 + kc) ^ ((row & 7) << 3);
        *(f16x8*)&lsA0[el] = *(const f16x8*)(Af + (arow0 + row) * 512 + kb + kc);
        *(f16x8*)&lsA1[el] = *(const f16x8*)(Af + (arow0 + 128 + row) * 512 + kb + kc);
        *(f16x8*)&lsB[el]  = *(const f16x8*)(Bw + (brow0 + row) * 512 + kb + kc);
      }
      __syncthreads();
#pragma unroll
      for (int k0 = 0; k0 < 64; k0 += 32) {
        const int kk = k0 + lq * 8;
        f16x8 af0[4], af1[4], bfr[2];
#pragma unroll
        for (int i = 0; i < 4; ++i) {
          int ra = wr + i * 16 + l15;
          int el = (ra * 64 + kk) ^ ((ra & 7) << 3);
          af0[i] = *(const f16x8*)&lsA0[el];
          af1[i] = *(const f16x8*)&lsA1[el];
        }
#pragma unroll
        for (int jt = 0; jt < 2; ++jt) {
          int rb = wc + jt * 16 + l15;
          bfr[jt] = *(const f16x8*)&lsB[(rb * 64 + kk) ^ ((rb & 7) << 3)];
        }
#pragma unroll
        for (int i = 0; i < 4; ++i)
#pragma unroll
          for (int jt = 0; jt < 2; ++jt) {
            acc0[i][jt] = mma_f16(af0[i], bfr[jt], acc0[i][jt]);
            acc1[i][jt] = mma_f16(af1[i], bfr[jt], acc1[i][jt]);
          }
      }
      __syncthreads();
    }
    // line-merged epilogue: both 64B halves of each 128B line back-to-back
    const float b0v = bias[brow0 + wc + l15];
    const float b1v = bias[brow0 + wc + 16 + l15];
#pragma unroll
    for (int i = 0; i < 4; ++i) {
#pragma unroll
      for (int r = 0; r < 4; ++r) {
        const size_t row = arow0 + wr + i * 16 + lq * 4 + r;
        float* pa = C + row * (size_t)NV + brow0 + wc + l15;
        st_nt(pa, acc0[i][0][r] + b0v);
        st_nt(pa + 16, acc0[i][1][r] + b1v);
        float* pb = pa + (size_t)128 * NV;
        st_nt(pb, acc1[i][0][r] + b0v);
        st_nt(pb + 16, acc1[i][1][r] + b1v);
      }
    }
  }
}

// ================= fused persistent kernel =================
__launch_bounds__(512, 1)
__global__ void k_main(
    const float* __restrict__ Wr, const float* __restrict__ Wz, const float* __restrict__ Wh,
    const float* __restrict__ Wrb, const float* __restrict__ Wzb, const float* __restrict__ Whb,
    const short* __restrict__ XeHi, const short* __restrict__ XeLo,
    short* X1Hi, short* X1Lo, _Float16* X1f16,
    short* h0Hi, short* h0Lo,
    short* rh0Hi, short* rh0Lo, short* rh1Hi, short* rh1Lo,
    float* z0, float* z1, float* hidOut,
    const _Float16* OWf, const float* outb, float* out,
    unsigned* flags, unsigned* tcnt) {
  __shared__ __align__(16) char pool[153600];
  short* lsHi = (short*)pool;                  // 64 KB weights hi
  short* lsLo = lsHi + 32 * 1024;              // 64 KB weights lo
  float* lsRed = (float*)(pool + 131072);      // 12 KB reduce scratch
  short* sH    = (short*)(pool + 131072);      // epilogue overlay (post-reduce)
  short* sL    = sH + 1024;
  float* sZA   = (float*)(pool + 131072);
  short* stH   = (short*)(pool + 143360);      // 2 KB prestage hi
  short* stL   = stH + 1024;                   // 2 KB prestage lo
  float* sZ    = (float*)(pool + 147456);      // 4 KB z prestage
  _Float16* sX = (_Float16*)(pool + 151552);   // 2 KB X1f16 stage

  const int wg = blockIdx.x;
  const int tid = threadIdx.x;
  const int wave = tid >> 6, lane = tid & 63, l15 = lane & 15, lq = lane >> 4;

  if (wg < 64) {
    // ===== l0A: layer-0 gates, 32 cols x 32 rows =====
    const int cg = wg >> 1, rh = wg & 1, jc = cg * 32, rowbase = rh * 32;
    const bool isR = (jc < 512);
    stage_weights(lsHi, lsLo, Wr, Wz, jc, tid);
    float biasL0, biasL1;
    {
      const int j0 = jc + l15, j1 = j0 + 16;
      biasL0 = (j0 < 512) ? Wrb[j0] : Wzb[j0 - 512];
      biasL1 = (j1 < 512) ? Wrb[j1] : Wzb[j1 - 512];
    }
    __syncthreads();
    for (int t = 0; t < NT; ++t) {
      f32x4 accH[2] = {}, accL[2] = {};
      mmaP32(XeHi + (size_t)t * SZ_H + rowbase * 512,
             XeLo + (size_t)t * SZ_H + rowbase * 512, 0,
             lsHi, lsLo, accH, accL, wave, l15, lq);   // static x-half (no deps)
      const short* hH = h0Hi + (size_t)t * SZ_H + rowbase * 512;
      const short* hL = h0Lo + (size_t)t * SZ_H + rowbase * 512;
      // MERGED wait: lanes 0-3 = slice producers; lane 4 = prestage producer
      {
        const int idx = lane & 7;
        int cgp = 4 * (wave >> 1) + (idx & 3);
        if (idx == 4 && isR) cgp = (jc >> 5);
        const unsigned* fp = &flags[(size_t)(128 + cgp * 2 + rh) * 32];
        wave_poll(fp, (unsigned)t);
      }
      // register-carried prestage (producer already confirmed by merged wait)
      i32x4 pre;
      const int pbuf = tid >> 7, pq = tid & 127, prow = pq >> 2, pc = pq & 3;
      if (isR && tid < 256)
        pre = *(const i32x4*)((pbuf ? hL : hH) + prow * 512 + jc + pc * 8);
      mmaP32(hH, hL, 512, lsHi, lsLo, accH, accL, wave, l15, lq);  // dependent h-half
      if (isR && tid < 256)
        *(i32x4*)&(pbuf ? stL : stH)[prow * 32 + pc * 8] = pre;
      f32x4 acc[2];
      reduce4(lsRed, accH, accL, acc, wave, l15, lq);
      if (wave < 2) {
#pragma unroll
        for (int ct = 0; ct < 2; ++ct) {
          const int jj = ct * 16 + l15;
          const float bv = ct ? biasL1 : biasL0;
#pragma unroll
          for (int r = 0; r < 4; ++r) {
            const int lb = wave * 16 + lq * 4 + r;
            const float s = fast_sigmoid(acc[ct][r] + bv);
            if (isR) {
              const float hv = bf2f((unsigned short)stH[lb * 32 + jj]) +
                               bf2f((unsigned short)stL[lb * 32 + jj]);
              short hi, lo; split2(s * hv, &hi, &lo);
              sH[lb * 32 + jj] = hi; sL[lb * 32 + jj] = lo;
            } else {
              sZA[lb * 32 + jj] = s;
            }
          }
        }
      }
      __syncthreads();
      if (isR) {
        if (tid < 256) {
          i32x4 v = *(const i32x4*)&(pbuf ? sL : sH)[prow * 32 + pc * 8];
          st_sc128((pbuf ? rh0Lo : rh0Hi) + (size_t)t * SZ_H +
                   (size_t)(rowbase + prow) * 512 + jc + pc * 8, v);
        }
      } else {
        if (tid < 256) {
          const int row = tid >> 3, c = tid & 7;
          i32x4 v = *(const i32x4*)&sZA[row * 32 + c * 4];
          st_sc128(z0 + (size_t)t * SZ_H + (size_t)(rowbase + row) * 512 +
                   (jc - 512) + c * 4, v);
        }
      }
      publish(flags, wg, (unsigned)(t + 1));
    }
  } else if (wg < 128) {
    // ===== l1A: layer-1 gates, 32 cols x 32 rows, full-k (per-wave dataflow) =====
    const int idx0 = wg - 64, cg = idx0 >> 1, rh = idx0 & 1, jc = cg * 32, rowbase = (idx0 & 1) * 32;
    const bool isR = (jc < 512);
    stage_weights(lsHi, lsLo, Wr + (size_t)512 * 1024, Wz + (size_t)512 * 1024, jc, tid);
    float biasL0, biasL1;
    {
      const int j0 = jc + l15, j1 = j0 + 16;
      biasL0 = (j0 < 512) ? Wrb[512 + j0] : Wzb[512 + j0 - 512];
      biasL1 = (j1 < 512) ? Wrb[512 + j1] : Wzb[512 + j1 - 512];
    }
    __syncthreads();
    for (int t = 0; t < NT; ++t) {
      const short* xH = h0Hi + (size_t)(t + 1) * SZ_H;
      const short* xL = h0Lo + (size_t)(t + 1) * SZ_H;
      const short* hH = X1Hi + (size_t)t * SZ_H;
      const short* hL = X1Lo + (size_t)t * SZ_H;
      // MERGED per-wave wait: lanes 0-7 = this khalf's 8 slice producers;
      // lane 8 = prestage producer (l1B cg=jc>>5, thr t)
      const int khalf = wave >> 1, rhalf = wave & 1;
      {
        const int idx = lane & 15;
        const unsigned* fp; unsigned thr;
        if (idx == 8 && isR) {
          fp = &flags[(size_t)(160 + (jc >> 5) * 2 + rh) * 32]; thr = (unsigned)t;
        } else if (khalf < 2) {
          const int cgp = (khalf & 1) * 8 + (idx & 7);
          fp = &flags[(size_t)(128 + cgp * 2 + rh) * 32]; thr = (unsigned)(t + 1);
        } else {
          const int cgp = (khalf & 1) * 8 + (idx & 7);
          fp = &flags[(size_t)(160 + cgp * 2 + rh) * 32]; thr = (unsigned)t;
        }
        wave_poll(fp, thr);
      }
      // register-carried prestage (producer confirmed)
      i32x4 pre;
      const int pbuf = tid >> 7, pq = tid & 127, prow = pq >> 2, pc = pq & 3;
      if (isR && tid < 256)
        pre = *(const i32x4*)((pbuf ? hL : hH) +
                              (size_t)(rowbase + prow) * 512 + jc + pc * 8);
      f32x4 accH[2] = {}, accL[2] = {};
      {
        const short* pAH = (khalf < 2) ? xH : hH;
        const short* pAL = (khalf < 2) ? xL : hL;
        mmaD(pAH, pAL, (khalf & 1) * 256, khalf * 256, lsHi, lsLo,
             accH, accL, l15, lq, rhalf, rowbase);
      }
      if (isR && tid < 256)
        *(i32x4*)&(pbuf ? stL : stH)[prow * 32 + pc * 8] = pre;
      f32x4 acc[2];
      reduceD(lsRed, accH, accL, acc, wave, l15, lq);
      if (wave < 2) {
#pragma unroll
        for (int ct = 0; ct < 2; ++ct) {
          const int jj = ct * 16 + l15;
          const float bv = ct ? biasL1 : biasL0;
#pragma unroll
          for (int r = 0; r < 4; ++r) {
            const int lb = wave * 16 + lq * 4 + r;
            const float s = fast_sigmoid(acc[ct][r] + bv);
            if (isR) {
              const float hv = bf2f((unsigned short)stH[lb * 32 + jj]) +
                               bf2f((unsigned short)stL[lb * 32 + jj]);
              short hi, lo; split2(s * hv, &hi, &lo);
              sH[lb * 32 + jj] = hi; sL[lb * 32 + jj] = lo;
            } else {
              sZA[lb * 32 + jj] = s;
            }
          }
        }
      }
      __syncthreads();
      if (isR) {
        if (tid < 256) {
          i32x4 v = *(const i32x4*)&(pbuf ? sL : sH)[prow * 32 + pc * 8];
          st_sc128((pbuf ? rh1Lo : rh1Hi) + (size_t)t * SZ_H +
                   (size_t)(rowbase + prow) * 512 + jc + pc * 8, v);
        }
      } else {
        if (tid < 256) {
          const int row = tid >> 3, c = tid & 7;
          i32x4 v = *(const i32x4*)&sZA[row * 32 + c * 4];
          st_sc128(z1 + (size_t)t * SZ_H + (size_t)(rowbase + row) * 512 +
                   (jc - 512) + c * 4, v);
        }
      }
      publish(flags, wg, (unsigned)(t + 1));
    }
  } else if (wg < 192) {
    // ===== B classes: candidate + state, 32 cols x 32 rows (per-wave dataflow) =====
    const bool isL1 = (wg >= 160);
    const int idx0 = isL1 ? (wg - 160) : (wg - 128);
    const int cg = idx0 >> 1, rh = idx0 & 1, jc = cg * 32, rowbase = (idx0 & 1) * 32;
    const int layer = isL1 ? 1 : 0;
    stage_weights(lsHi, lsLo, Wh + (size_t)layer * 512 * 1024, nullptr, jc, tid);
    const float biasL0 = Whb[layer * 512 + jc + l15];
    const float biasL1 = Whb[layer * 512 + jc + 16 + l15];
    __syncthreads();
    short* myHi = isL1 ? X1Hi : h0Hi;
    short* myLo = isL1 ? X1Lo : h0Lo;
    const short* rhHi_ = isL1 ? rh1Hi : rh0Hi;
    const short* rhLo_ = isL1 ? rh1Lo : rh0Lo;
    const float* zArr = isL1 ? z1 : z0;
    const int fbase = isL1 ? 64 : 0;    // A-class flag base for this layer
    for (int t = 0; t < NT; ++t) {
      // prestage own hOld (self-produced, no wait)
      const int pbuf = tid >> 7, pq = tid & 127, prow = pq >> 2, pc = pq & 3;
      if (tid < 256) {
        const short* src = (pbuf ? myLo : myHi) + (size_t)t * SZ_H +
                           (size_t)(rowbase + prow) * 512 + jc + pc * 8;
        *(i32x4*)&(pbuf ? stL : stH)[prow * 32 + pc * 8] = *(const i32x4*)src;
      }
      f32x4 accH[2] = {}, accL[2] = {};
      if (isL1) {
        // x1(t)=h0(t+1): per-wave 4 l0B producers >= t+1
        wave_poll4(flags, 128, 4 * (wave >> 1), rh, (unsigned)(t + 1), lane);
        mmaP32(h0Hi + (size_t)(t + 1) * SZ_H + rowbase * 512,
               h0Lo + (size_t)(t + 1) * SZ_H + rowbase * 512, 0,
               lsHi, lsLo, accH, accL, wave, l15, lq);
      } else {
        mmaP32(XeHi + (size_t)t * SZ_H + rowbase * 512,
               XeLo + (size_t)t * SZ_H + rowbase * 512, 0,
               lsHi, lsLo, accH, accL, wave, l15, lq);   // static x-half
      }
      // MERGED wait: lanes 0-3 = rh slice producers; lane 4 = z producer (same thr)
      {
        const int idx = lane & 7;
        int cgp = 4 * (wave >> 1) + (idx & 3);
        if (idx == 4) cgp = 16 + (jc >> 5);
        const unsigned* fp = &flags[(size_t)(fbase + cgp * 2 + rh) * 32];
        wave_poll(fp, (unsigned)(t + 1));
      }
      // register-carried z-stage (producer confirmed)
      f32x4 zv;
      const int zrow = tid >> 3, zc = tid & 7;
      if (tid < 256)
        zv = *(const f32x4*)(zArr + (size_t)t * SZ_H +
                             (size_t)(rowbase + zrow) * 512 + jc + zc * 4);
      mmaP32(rhHi_ + (size_t)t * SZ_H + rowbase * 512,
             rhLo_ + (size_t)t * SZ_H + rowbase * 512, 512,
             lsHi, lsLo, accH, accL, wave, l15, lq);     // dependent rh-half
      if (tid < 256)
        *(f32x4*)&sZ[zrow * 32 + zc * 4] = zv;
      f32x4 acc[2];
      reduce4(lsRed, accH, accL, acc, wave, l15, lq);
      if (wave < 2) {
#pragma unroll
        for (int ct = 0; ct < 2; ++ct) {
          const int jj = ct * 16 + l15, j = jc + jj;
          const float bv = ct ? biasL1 : biasL0;
#pragma unroll
          for (int r = 0; r < 4; ++r) {
            const int lb = wave * 16 + lq * 4 + r;
            const float hh = fast_tanh(acc[ct][r] + bv);
            const float z = sZ[lb * 32 + jj];
            const float ho = bf2f((unsigned short)stH[lb * 32 + jj]) +
                             bf2f((unsigned short)stL[lb * 32 + jj]);
            const float hn = (1.0f - z) * ho + z * hh;
            short hi, lo; split2(hn, &hi, &lo);
            sH[lb * 32 + jj] = hi; sL[lb * 32 + jj] = lo;
            if (isL1) sX[lb * 32 + jj] = (_Float16)hn;
            if (t == NT - 1)
              hidOut[(size_t)layer * SZ_H + (size_t)(rowbase + lb) * 512 + j] = hn;
          }
        }
      }
      __syncthreads();
      if (tid < 256) {
        i32x4 v = *(const i32x4*)&(pbuf ? sL : sH)[prow * 32 + pc * 8];
        st_sc128((pbuf ? myLo : myHi) + (size_t)(t + 1) * SZ_H +
                 (size_t)(rowbase + prow) * 512 + jc + pc * 8, v);
      } else if (isL1 && tid < 384) {
        const int q = tid - 256, row = q >> 2, c = q & 3;
        i32x4 v = *(const i32x4*)&sX[row * 32 + c * 8];
        st_sc128(X1f16 + (size_t)t * SZ_H + (size_t)(rowbase + row) * 512 + jc + c * 8, v);
      }
      publish(flags, wg, (unsigned)(t + 1));
    }
  }
  // ===== everyone converges on the GEMM (dedicated wgs 192..255 start now) =====
  gemm_loop(pool, tid, X1f16, OWf, outb, out, flags, tcnt);
}

// ---------------- launcher ----------------
extern "C" void kernel_launch(void* const* d_in, const int* in_sizes, int n_in,
                              void* d_out, int out_size, void* d_ws, size_t ws_size,
                              hipStream_t stream) {
  (void)in_sizes; (void)n_in; (void)out_size; (void)ws_size;
  const int*   toks = (const int*)d_in[0];
  const float* hid  = (const float*)d_in[1];
  const float* emb  = (const float*)d_in[2];
  const float* Wr   = (const float*)d_in[3];
  const float* Wrb  = (const float*)d_in[4];
  const float* Wz   = (const float*)d_in[5];
  const float* Wzb  = (const float*)d_in[6];
  const float* Wh   = (const float*)d_in[7];
  const float* Whb  = (const float*)d_in[8];
  const float* outw = (const float*)d_in[9];
  const float* outb = (const float*)d_in[10];
  float* out = (float*)d_out;

  char* base = (char*)d_ws;
  size_t off = 0;
  auto carve = [&](size_t bytes) -> char* {
    char* r = base + off;
    off = (off + bytes + 255) & ~(size_t)255;
    return r;
  };
  _Float16* OWf   = (_Float16*)carve(SZ_OW * 2);
  short*    XeHi  = (short*)carve(SZ_XE * 2);
  short*    XeLo  = (short*)carve(SZ_XE * 2);
  short*    X1Hi  = (short*)carve((size_t)(NT + 1) * SZ_H * 2);
  short*    X1Lo  = (short*)carve((size_t)(NT + 1) * SZ_H * 2);
  _Float16* X1f16 = (_Float16*)carve((size_t)NT * SZ_H * 2);
  short*    h0Hi  = (short*)carve((size_t)(NT + 1) * SZ_H * 2);
  short*    h0Lo  = (short*)carve((size_t)(NT + 1) * SZ_H * 2);
  short*    rh0Hi = (short*)carve((size_t)NT * SZ_H * 2);
  short*    rh0Lo = (short*)carve((size_t)NT * SZ_H * 2);
  short*    rh1Hi = (short*)carve((size_t)NT * SZ_H * 2);
  short*    rh1Lo = (short*)carve((size_t)NT * SZ_H * 2);
  float*    z0    = (float*)carve((size_t)NT * SZ_H * 4);
  float*    z1    = (float*)carve((size_t)NT * SZ_H * 4);
  unsigned* flags = (unsigned*)carve(32768);   // 192 slots * 128B
  unsigned* tcnt  = (unsigned*)carve(256);

  hipMemsetAsync(flags, 0, 32768, stream);
  hipMemsetAsync(tcnt, 0, 256, stream);

  k_prep<<<2048, 256, 0, stream>>>(outw, toks, emb, hid,
                                   OWf, XeHi, XeLo, X1Hi, X1Lo, h0Hi, h0Lo);

  k_main<<<256, 512, 0, stream>>>(
      Wr, Wz, Wh, Wrb, Wzb, Whb, XeHi, XeLo,
      X1Hi, X1Lo, X1f16, h0Hi, h0Lo,
      rh0Hi, rh0Lo, rh1Hi, rh1Lo, z0, z1,
      out + LOGITS, OWf, outb, out, flags, tcnt);
}